// Round 11
// baseline (7775.143 us; speedup 1.0000x reference)
//
#include <hip/hip_runtime.h>
#include <math.h>

#define BATCH 128
#define CCH 5
#define SEQ 512
#define UNITS 256
#define RU 512

#define ENC_N 33554432   // BATCH*SEQ*RU floats

typedef float v2f __attribute__((ext_vector_type(2)));

__device__ __forceinline__ float sigmoidf_(float v) {
    return 1.0f / (1.0f + __expf(-v));
}
__device__ __forceinline__ float tanhf_(float v) {
    float e = __expf(2.0f * v);
    return 1.0f - 2.0f / (e + 1.0f);
}
__device__ __forceinline__ void astoref(float* p, float v) {
    __hip_atomic_store(p, v, __ATOMIC_RELAXED, __HIP_MEMORY_SCOPE_AGENT);
}
__device__ __forceinline__ void astorei(int* p, int v) {
    __hip_atomic_store(p, v, __ATOMIC_RELAXED, __HIP_MEMORY_SCOPE_AGENT);
}
__device__ __forceinline__ unsigned long long aloadu64(const unsigned long long* p) {
    return __hip_atomic_load(p, __ATOMIC_RELAXED, __HIP_MEMORY_SCOPE_AGENT);
}
__device__ __forceinline__ int aloadi(const int* p) {
    return __hip_atomic_load(p, __ATOMIC_RELAXED, __HIP_MEMORY_SCOPE_AGENT);
}

// packed fp32 FMA: acc.{x,y} += h2.{x,y} * w2.{lo|hi}
#define PK_LO(ACC, H2, W2) \
    asm("v_pk_fma_f32 %0, %1, %2, %0 op_sel:[0,0,0] op_sel_hi:[1,0,1]" \
        : "+v"(ACC) : "v"(H2), "v"(W2))
#define PK_HI(ACC, H2, W2) \
    asm("v_pk_fma_f32 %0, %1, %2, %0 op_sel:[0,1,0] op_sel_hi:[1,1,1]" \
        : "+v"(ACC) : "v"(H2), "v"(W2))

// transposed h layouts: hT[u][b], padded every 16 (dec) / 8 (enc) rows
#define HADDR_D(u, b) ((u) * 8 + ((u) >> 4) * 2 + (b))
#define HADDR_E(u, b) ((u) * 8 + ((u) >> 3) * 2 + (b))

// 5-stage butterfly over 32-lane half-wave: acc[p][j] (.x=batch2p,.y=batch2p+1,
// gate j) -> lane s=l&31 ends with z[b=s>>2][gate=s&3]. Reg/shfl only.
#define BUTTERFLY(ACC, L, ZRES) { \
    v2f m1_[2][4]; \
    const bool k4_ = ((L) & 16); \
    _Pragma("unroll") \
    for (int p2_ = 0; p2_ < 2; ++p2_) { \
        _Pragma("unroll") \
        for (int j_ = 0; j_ < 4; ++j_) { \
            v2f lo_ = ACC[p2_][j_], hi_ = ACC[2 + p2_][j_]; \
            float olx = __shfl(lo_.x, (L) ^ 16), oly = __shfl(lo_.y, (L) ^ 16); \
            float ohx = __shfl(hi_.x, (L) ^ 16), ohy = __shfl(hi_.y, (L) ^ 16); \
            m1_[p2_][j_].x = k4_ ? (hi_.x + ohx) : (lo_.x + olx); \
            m1_[p2_][j_].y = k4_ ? (hi_.y + ohy) : (lo_.y + oly); \
        } \
    } \
    v2f m2_[4]; \
    const bool k3_ = ((L) & 8); \
    _Pragma("unroll") \
    for (int j_ = 0; j_ < 4; ++j_) { \
        v2f lo_ = m1_[0][j_], hi_ = m1_[1][j_]; \
        float olx = __shfl(lo_.x, (L) ^ 8), oly = __shfl(lo_.y, (L) ^ 8); \
        float ohx = __shfl(hi_.x, (L) ^ 8), ohy = __shfl(hi_.y, (L) ^ 8); \
        m2_[j_].x = k3_ ? (hi_.x + ohx) : (lo_.x + olx); \
        m2_[j_].y = k3_ ? (hi_.y + ohy) : (lo_.y + oly); \
    } \
    float m3_[4]; \
    const bool k2_ = ((L) & 4); \
    _Pragma("unroll") \
    for (int j_ = 0; j_ < 4; ++j_) { \
        float xo_ = __shfl(m2_[j_].x, (L) ^ 4); \
        float yo_ = __shfl(m2_[j_].y, (L) ^ 4); \
        m3_[j_] = k2_ ? (m2_[j_].y + yo_) : (m2_[j_].x + xo_); \
    } \
    float m4_[2]; \
    const bool k1_ = ((L) & 2); \
    _Pragma("unroll") \
    for (int jj_ = 0; jj_ < 2; ++jj_) { \
        float a_ = m3_[jj_], b_ = m3_[2 + jj_]; \
        float ao_ = __shfl(a_, (L) ^ 2), bo_ = __shfl(b_, (L) ^ 2); \
        m4_[jj_] = k1_ ? (b_ + bo_) : (a_ + ao_); \
    } \
    { \
        float a_ = m4_[0], b_ = m4_[1]; \
        float ao_ = __shfl(a_, (L) ^ 1), bo_ = __shfl(b_, (L) ^ 1); \
        ZRES = ((L) & 1) ? (b_ + bo_) : (a_ + ao_); \
    } \
}

// ---------------------------------------------------------------------------
// Encoder: 256 blocks = dir(2) x tile(16; 8 batches) x slice(8; 32 units).
// Lane (w,l): half-wave u_idx=w*2+(l>>5) picks the unit; s=l&31 picks 8 rows;
// 4 gate-cols of that unit in regs. Butterfly reduce -> 1 transcendental/lane
// -> 4-shfl gather -> gates. 2 barriers/step. h transposed+padded in LDS.
// ---------------------------------------------------------------------------
__global__ __attribute__((amdgpu_flat_work_group_size(1024, 1024),
                          amdgpu_waves_per_eu(4, 4)))
void encoder_kernel(const float* __restrict__ x,
                    const float* __restrict__ Wf_k, const float* __restrict__ Wf_r,
                    const float* __restrict__ bf,
                    const float* __restrict__ Wb_k, const float* __restrict__ Wb_r,
                    const float* __restrict__ bb,
                    float* __restrict__ enc, float* __restrict__ h_ex,
                    int* __restrict__ flags)
{
    const int bid  = blockIdx.x;
    const int dir  = bid >> 7;
    const int tile = (bid >> 3) & 15;
    const int jsl  = bid & 7;
    const int grp  = dir * 16 + tile;
    const int bg0  = tile * 8;
    const float* __restrict__ Wk   = dir ? Wb_k : Wf_k;
    const float* __restrict__ Wr   = dir ? Wb_r : Wf_r;
    const float* __restrict__ bias = dir ? bb : bf;
    const int tid = threadIdx.x;
    const int wv  = tid >> 6;
    const int l   = tid & 63;
    const int s   = l & 31;
    const int u_idx = wv * 2 + (l >> 5);      // 0..31
    const int U     = jsl * 32 + u_idx;       // unit in [0,256)
    const int b_ln  = s >> 2;                 // lane's output batch
    const int g_ln  = s & 3;                  // lane's gate

    __shared__ float hTe[2][2112];            // 16.9 KB  (u-major, +2 pad/8 rows)
    __shared__ unsigned char mL[8][SEQ];      // 4 KB
    __shared__ float xLe[8][8];

    // ---- one-time staging ----
    for (int i = tid; i < 2 * 2112; i += 1024) ((float*)hTe)[i] = 0.0f;
    for (int i = tid; i < 8 * SEQ; i += 1024) {
        int b = i >> 9, tt = i & (SEQ - 1);
        mL[b][tt] = (x[((size_t)((bg0 + b) * CCH) * SEQ + tt) * 3 + 2] != 0.0f) ? 1 : 0;
    }
    // weights: rows s*8..+7, all 4 gate-cols of unit U (gate stride 256)
    v2f w01[8], w23[8];
    {
        const float* wb = Wr + (size_t)(s * 8) * 1024 + U;
        #pragma unroll
        for (int r = 0; r < 8; ++r) {
            v2f a; a.x = wb[(size_t)r * 1024];        a.y = wb[(size_t)r * 1024 + 256];
            v2f c; c.x = wb[(size_t)r * 1024 + 512];  c.y = wb[(size_t)r * 1024 + 768];
            w01[r] = a; w23[r] = c;
        }
    }
    const float biasR = bias[g_ln * 256 + U];
    float wkR[CCH];
    #pragma unroll
    for (int c = 0; c < CCH; ++c) wkR[c] = Wk[c * 1024 + g_ln * 256 + U];
    float creg = 0.0f, hreg = 0.0f;
    __syncthreads();

    for (int t = 0; t < SEQ; ++t) {
        const int cur = t & 1;
        const int ts = dir ? (SEQ - 1 - t) : t;
        if (t > 0) {
            // wave w loads units w*16..+16 (produced by slice w>>1)
            const int* fp = &flags[(grp * 8 + (wv >> 1)) * 32];
            if (l == 0) {
                int guard = 0;
                while (aloadi(fp) < t && guard < (1 << 26)) {
                    __builtin_amdgcn_s_sleep(1); ++guard;
                }
            }
            int u = wv * 16 + (l >> 2), b0 = (l & 3) * 2;
            const unsigned long long* hsrc = (const unsigned long long*)
                &h_ex[(size_t)(dir * 2 + ((t - 1) & 1)) * 32768 + tile * 2048
                      + (size_t)u * 8 + b0];
            unsigned long long v = aloadu64(hsrc);
            *(unsigned long long*)&hTe[cur][HADDR_E(u, b0)] = v;
        }
        if (tid >= 960 && tid < 1000) {  // wave 15: x_t for the 8 batches
            int i = tid - 960, b = i / 5, c = i - b * 5;
            xLe[b][c] = x[((size_t)((bg0 + b) * CCH + c) * SEQ + ts) * 3];
        }
        __syncthreads();   // B1 (h + x ready)

        // z-core: 8 rows x 4 gate-cols x 8 batches, pk FMA
        v2f acc[4][4];
        #pragma unroll
        for (int p = 0; p < 4; ++p)
            #pragma unroll
            for (int j = 0; j < 4; ++j) acc[p][j] = (v2f){0.f, 0.f};
        const float* hrow = &hTe[cur][s * 66];
        #pragma unroll
        for (int rr = 0; rr < 8; ++rr) {
            const v2f* hp = (const v2f*)(hrow + rr * 8);
            v2f a = w01[rr], c = w23[rr];
            #pragma unroll
            for (int p = 0; p < 4; ++p) {
                v2f h2 = hp[p];
                PK_LO(acc[p][0], h2, a);
                PK_HI(acc[p][1], h2, a);
                PK_LO(acc[p][2], h2, c);
                PK_HI(acc[p][3], h2, c);
            }
        }

        float z;
        BUTTERFLY(acc, l, z)
        z += biasR;
        #pragma unroll
        for (int c = 0; c < CCH; ++c) z = fmaf(xLe[b_ln][c], wkR[c], z);
        float T = (g_ln == 2) ? tanhf_(z) : sigmoidf_(z);
        const int base = l & ~3;
        float Ti = __shfl(T, base);
        float Tf = __shfl(T, base + 1);
        float Tg = __shfl(T, base + 2);
        float To = __shfl(T, base + 3);
        float cn = Tf * creg + Ti * Tg;
        float hn = To * tanhf_(cn);
        int m = mL[b_ln][ts];
        float h2v = m ? hn : hreg;
        float c2v = m ? cn : creg;
        creg = c2v; hreg = h2v;
        if ((l & 3) == 0) {
            astoref(&h_ex[(size_t)(dir * 2 + cur) * 32768 + tile * 2048
                          + (size_t)U * 8 + b_ln], h2v);
            enc[((size_t)(bg0 + b_ln) * SEQ + ts) * RU + dir * UNITS + U] = h2v;
        }
        __syncthreads();   // B2 (drains publishes)
        if (tid == 0) astorei(&flags[(grp * 8 + jsl) * 32], t + 1);
    }
}

// ---------------------------------------------------------------------------
// Attention precompute (alpha constant over decoder time). One block/batch.
// ---------------------------------------------------------------------------
__global__ __launch_bounds__(256)
void attn_kernel(const float* __restrict__ enc,
                 const float* __restrict__ W_attn, const float* __restrict__ b_attn,
                 const float* __restrict__ W_dense, const float* __restrict__ b_dense,
                 const float* __restrict__ x,
                 float* __restrict__ attn_ws, float* __restrict__ hidden_ws,
                 float* __restrict__ xbuf, float* __restrict__ xconst)
{
    const int b = blockIdx.x;
    const int tid = threadIdx.x;
    const int lane = tid & 63;
    const int wv = tid >> 6;

    __shared__ float WeL[RU];
    __shared__ float scoresL[SEQ];
    __shared__ float red[256];
    __shared__ float attnL[RU];

    WeL[tid]       = W_attn[CCH + tid];
    WeL[tid + 256] = W_attn[CCH + tid + 256];
    __syncthreads();

    const float* __restrict__ encb = enc + (size_t)b * SEQ * RU;
    const float batt = b_attn[0];

    for (int s = wv; s < SEQ; s += 4) {
        const float* row = encb + (size_t)s * RU;
        float p = 0.0f;
        #pragma unroll
        for (int i = 0; i < 8; ++i) {
            int d = lane * 8 + i;
            p = fmaf(row[d], WeL[d], p);
        }
        #pragma unroll
        for (int o = 32; o; o >>= 1) p += __shfl_xor(p, o);
        if (lane == 0) scoresL[s] = p + batt;
    }
    __syncthreads();

    float m = fmaxf(scoresL[tid], scoresL[tid + 256]);
    red[tid] = m;
    __syncthreads();
    for (int st = 128; st; st >>= 1) {
        if (tid < st) red[tid] = fmaxf(red[tid], red[tid + st]);
        __syncthreads();
    }
    const float mx = red[0];
    __syncthreads();
    float e0 = __expf(scoresL[tid] - mx);
    float e1 = __expf(scoresL[tid + 256] - mx);
    red[tid] = e0 + e1;
    __syncthreads();
    for (int st = 128; st; st >>= 1) {
        if (tid < st) red[tid] += red[tid + st];
        __syncthreads();
    }
    const float sinv = 1.0f / red[0];
    __syncthreads();
    scoresL[tid]       = e0 * sinv;
    scoresL[tid + 256] = e1 * sinv;
    __syncthreads();

    float a0 = 0.0f, a1 = 0.0f;
    for (int s = 0; s < SEQ; ++s) {
        float al = scoresL[s];
        a0 = fmaf(al, encb[(size_t)s * RU + tid], a0);
        a1 = fmaf(al, encb[(size_t)s * RU + tid + 256], a1);
    }
    attn_ws[(size_t)b * RU + tid]       = a0;
    attn_ws[(size_t)b * RU + tid + 256] = a1;
    attnL[tid] = a0;
    attnL[tid + 256] = a1;
    hidden_ws[(size_t)b * RU + tid]       = encb[(size_t)(SEQ - 1) * RU + tid];
    hidden_ws[(size_t)b * RU + tid + 256] = encb[(size_t)(SEQ - 1) * RU + tid + 256];
    if (tid < CCH) xbuf[b * CCH + tid] = x[((size_t)(b * CCH + tid) * SEQ + 0) * 3];
    __syncthreads();

    if (tid < CCH) {
        float acc = b_dense[tid];
        for (int d = 0; d < RU; ++d)
            acc = fmaf(attnL[d], W_dense[(RU + d) * CCH + tid], acc);
        xconst[b * CCH + tid] = acc;
    }
}

// ---------------------------------------------------------------------------
// Decoder: 256 blocks = tile(16; 8 batches) x slice(16; 32 units). Lane owns
// 16 rows x 4 gate-cols of one unit (half-wave); butterfly reduce; 3 barriers.
// ---------------------------------------------------------------------------
__global__ __attribute__((amdgpu_flat_work_group_size(1024, 1024),
                          amdgpu_waves_per_eu(4, 4)))
void decoder_kernel(const float* __restrict__ Wd_k, const float* __restrict__ Wd_r,
                    const float* __restrict__ bd,
                    const float* __restrict__ W_dense,
                    const float* __restrict__ attn_ws, const float* __restrict__ hidden_ws,
                    const float* __restrict__ xbuf, const float* __restrict__ xconst,
                    float* __restrict__ h_ex, int* __restrict__ flags,
                    float* __restrict__ out)
{
    const int bid  = blockIdx.x;
    const int tile = bid >> 4;
    const int jsl  = bid & 15;
    const int bg0  = tile * 8;
    const int tid  = threadIdx.x;
    const int wv   = tid >> 6;
    const int l    = tid & 63;
    const int s    = l & 31;
    const int u_idx = wv * 2 + (l >> 5);      // 0..31
    const int U     = jsl * 32 + u_idx;       // unit in [0,512)
    const int b_ln  = s >> 2;
    const int g_ln  = s & 3;

    __shared__ float hT[2][4160];             // 33.3 KB (u-major, +2 pad/16 rows)
    __shared__ float WdL[RU * CCH];           // 10 KB
    __shared__ float xL[8][8], xcL[8][8];

    // ---- one-time staging ----
    for (int i = tid; i < RU * CCH; i += 1024) WdL[i] = W_dense[i];
    if (tid < 64) {
        int b = tid >> 3, c = tid & 7;
        if (c < 5) {
            xL[b][c]  = xbuf[(bg0 + b) * CCH + c];
            xcL[b][c] = xconst[(bg0 + b) * CCH + c];
        }
    }
    for (int e = tid; e < 4096; e += 1024) {  // t=0 h from hidden_ws
        int u = e >> 3, b = e & 7;
        hT[0][HADDR_D(u, b)] = hidden_ws[(size_t)(bg0 + b) * RU + u];
    }
    // weights: rows s*16..+15, all 4 gate-cols of unit U (gate stride 512)
    v2f w01[16], w23[16];
    {
        const float* wb = Wd_r + (size_t)(s * 16) * 2048 + U;
        #pragma unroll
        for (int r = 0; r < 16; ++r) {
            v2f a; a.x = wb[(size_t)r * 2048];         a.y = wb[(size_t)r * 2048 + 512];
            v2f c; c.x = wb[(size_t)r * 2048 + 1024];  c.y = wb[(size_t)r * 2048 + 1536];
            w01[r] = a; w23[r] = c;
        }
    }
    const float biasR = bd[g_ln * 512 + U];
    float wkR[CCH];
    #pragma unroll
    for (int c = 0; c < CCH; ++c) wkR[c] = Wd_k[c * 2048 + g_ln * 512 + U];
    const float attR = attn_ws[(size_t)(bg0 + b_ln) * RU + U];
    __syncthreads();

    for (int t = 0; t < SEQ - 1; ++t) {
        const int cur = t & 1;
        if (t > 0) {
            // wave w loads units w*32..+32 (produced by slice w)
            const int* fp = &flags[(tile * 16 + wv) * 32];
            if (l == 0) {
                int guard = 0;
                while (aloadi(fp) < t && guard < (1 << 26)) {
                    __builtin_amdgcn_s_sleep(1); ++guard;
                }
            }
            int u = wv * 32 + (l >> 1), b0 = (l & 1) * 4;
            const unsigned long long* hsrc = (const unsigned long long*)
                &h_ex[(size_t)((t - 1) & 1) * 65536 + tile * 4096
                      + (size_t)u * 8 + b0];
            unsigned long long v0 = aloadu64(hsrc);
            unsigned long long v1 = aloadu64(hsrc + 1);
            *(unsigned long long*)&hT[cur][HADDR_D(u, b0)]     = v0;
            *(unsigned long long*)&hT[cur][HADDR_D(u, b0 + 2)] = v1;
        }
        __syncthreads();   // B1

        // x_t dense-reduce (reads hT; overlapped with z-core issue window)
        if (t > 0) {
            for (int it = wv; it < 40; it += 16) {
                int bb = it / 5, c = it - bb * 5;
                float p = 0.f;
                #pragma unroll
                for (int q = 0; q < 8; ++q) {
                    int uu = l + (q << 6);
                    p = fmaf(hT[cur][HADDR_D(uu, bb)], WdL[uu * CCH + c], p);
                }
                #pragma unroll
                for (int o = 32; o; o >>= 1) p += __shfl_xor(p, o);
                if (l == 0) xL[bb][c] = p + xcL[bb][c];
            }
        }

        // z-core: 16 rows x 4 gate-cols x 8 batches, pk FMA
        v2f acc[4][4];
        #pragma unroll
        for (int p = 0; p < 4; ++p)
            #pragma unroll
            for (int j = 0; j < 4; ++j) acc[p][j] = (v2f){0.f, 0.f};
        const float* hrow = &hT[cur][s * 130];
        #pragma unroll
        for (int rr = 0; rr < 16; ++rr) {
            const v2f* hp = (const v2f*)(hrow + rr * 8);
            v2f a = w01[rr], c = w23[rr];
            #pragma unroll
            for (int p = 0; p < 4; ++p) {
                v2f h2 = hp[p];
                PK_LO(acc[p][0], h2, a);
                PK_HI(acc[p][1], h2, a);
                PK_LO(acc[p][2], h2, c);
                PK_HI(acc[p][3], h2, c);
            }
        }
        __syncthreads();   // B2 (xL ready for gate phase)

        float z;
        BUTTERFLY(acc, l, z)
        z += biasR;
        #pragma unroll
        for (int c = 0; c < CCH; ++c) z = fmaf(xL[b_ln][c], wkR[c], z);
        float T = (g_ln == 2) ? tanhf_(z) : sigmoidf_(z);
        const int base = l & ~3;
        float Ti = __shfl(T, base);
        float Tf = __shfl(T, base + 1);
        float Tg = __shfl(T, base + 2);
        float To = __shfl(T, base + 3);
        float cn = Tf * attR + Ti * Tg;
        float hn = To * tanhf_(cn);
        if ((l & 3) == 0)
            astoref(&h_ex[(size_t)cur * 65536 + tile * 4096
                          + (size_t)U * 8 + b_ln], hn);
        __syncthreads();   // B3 (drains publishes)
        if (tid == 0) astorei(&flags[(tile * 16 + jsl) * 32], t + 1);
        // out-write off the drain path (xL stable until after next B1)
        if (t > 0 && jsl == 0 && tid >= 256 && tid < 296) {
            int i = tid - 256, bb = i / 5, c = i - bb * 5;
            out[(size_t)((bg0 + bb) * CCH + c) * (SEQ - 1) + (t - 1)] = xL[bb][c];
        }
    }

    // ---- epilogue: t = 511 -> out[510] from h_511 (only jsl==0 blocks) ----
    if (jsl == 0) {
        const int t = SEQ - 1;          // 511
        const int cur = t & 1;          // 1
        const int* fp = &flags[(tile * 16 + wv) * 32];
        if (l == 0) {
            int guard = 0;
            while (aloadi(fp) < t && guard < (1 << 26)) {
                __builtin_amdgcn_s_sleep(1); ++guard;
            }
        }
        int u = wv * 32 + (l >> 1), b0 = (l & 1) * 4;
        const unsigned long long* hsrc = (const unsigned long long*)
            &h_ex[(size_t)((t - 1) & 1) * 65536 + tile * 4096
                  + (size_t)u * 8 + b0];
        unsigned long long v0 = aloadu64(hsrc);
        unsigned long long v1 = aloadu64(hsrc + 1);
        *(unsigned long long*)&hT[cur][HADDR_D(u, b0)]     = v0;
        *(unsigned long long*)&hT[cur][HADDR_D(u, b0 + 2)] = v1;
        __syncthreads();
        for (int it = wv; it < 40; it += 16) {
            int bb = it / 5, c = it - bb * 5;
            float p = 0.f;
            #pragma unroll
            for (int q = 0; q < 8; ++q) {
                int uu = l + (q << 6);
                p = fmaf(hT[cur][HADDR_D(uu, bb)], WdL[uu * CCH + c], p);
            }
            #pragma unroll
            for (int o = 32; o; o >>= 1) p += __shfl_xor(p, o);
            if (l == 0)
                out[(size_t)((bg0 + bb) * CCH + c) * (SEQ - 1) + (t - 1)]
                    = p + xcL[bb][c];
        }
    }
}

// ---------------------------------------------------------------------------
extern "C" void kernel_launch(void* const* d_in, const int* in_sizes, int n_in,
                              void* d_out, int out_size, void* d_ws, size_t ws_size,
                              hipStream_t stream)
{
    const float* x       = (const float*)d_in[0];
    const float* Wf_k    = (const float*)d_in[1];
    const float* Wf_r    = (const float*)d_in[2];
    const float* bf      = (const float*)d_in[3];
    const float* Wb_k    = (const float*)d_in[4];
    const float* Wb_r    = (const float*)d_in[5];
    const float* bb      = (const float*)d_in[6];
    const float* Wd_k    = (const float*)d_in[7];
    const float* Wd_r    = (const float*)d_in[8];
    const float* bd      = (const float*)d_in[9];
    const float* W_attn  = (const float*)d_in[10];
    const float* b_attn  = (const float*)d_in[11];
    const float* W_dense = (const float*)d_in[12];
    const float* b_dense = (const float*)d_in[13];
    float* out = (float*)d_out;

    float* ws = (float*)d_ws;
    // persistent (attn -> decoder) region after enc
    float* enc      = ws;                          // [0, ENC_N)
    float* attn_p   = ws + ENC_N;                  // 65536 floats
    float* hidden_p = ws + ENC_N + 65536;          // 65536 floats
    float* xbuf_p   = ws + ENC_N + 131072;         // 640
    float* xconst_p = ws + ENC_N + 131712;         // 640
    // encoder-phase overlays (dead before attn_kernel writes the same region)
    float* h_ex_e   = ws + ENC_N;                  // 4 x 16 x 256 x 8 = 131072 floats
    int*   flag_e   = (int*)(ws + ENC_N + 131072); // 32 grp x 8 x 32 = 8192 ints
    // decoder-phase overlays on dead enc region
    int*   flag_d   = (int*)ws;                    // 16 tile x 16 x 32 = 8192 ints
    float* h_ex_d   = ws + 8192;                   // 2 x 16 x 512 x 8 = 131072 floats

    hipMemsetAsync(flag_e, 0, 8192 * sizeof(int), stream);
    encoder_kernel<<<256, 1024, 0, stream>>>(x, Wf_k, Wf_r, bf, Wb_k, Wb_r, bb,
                                             enc, h_ex_e, flag_e);
    attn_kernel<<<BATCH, 256, 0, stream>>>(enc, W_attn, b_attn, W_dense, b_dense, x,
                                           attn_p, hidden_p, xbuf_p, xconst_p);
    hipMemsetAsync(flag_d, 0, 8192 * sizeof(int), stream);
    decoder_kernel<<<256, 1024, 0, stream>>>(Wd_k, Wd_r, bd, W_dense,
                                             attn_p, hidden_p, xbuf_p, xconst_p,
                                             h_ex_d, flag_d, out);
}

// Round 12
// 5735.840 us; speedup vs baseline: 1.3555x; 1.3555x over previous
//
#include <hip/hip_runtime.h>
#include <math.h>

#define BATCH 128
#define CCH 5
#define SEQ 512
#define UNITS 256
#define RU 512

#define ENC_N 33554432   // BATCH*SEQ*RU floats

__device__ __forceinline__ float sigmoidf_(float v) {
    return 1.0f / (1.0f + __expf(-v));
}
__device__ __forceinline__ float tanhf_(float v) {
    float e = __expf(2.0f * v);
    return 1.0f - 2.0f / (e + 1.0f);
}
__device__ __forceinline__ void astoref(float* p, float v) {
    __hip_atomic_store(p, v, __ATOMIC_RELAXED, __HIP_MEMORY_SCOPE_AGENT);
}
__device__ __forceinline__ void astorei(int* p, int v) {
    __hip_atomic_store(p, v, __ATOMIC_RELAXED, __HIP_MEMORY_SCOPE_AGENT);
}
__device__ __forceinline__ unsigned long long aloadu64(const unsigned long long* p) {
    return __hip_atomic_load(p, __ATOMIC_RELAXED, __HIP_MEMORY_SCOPE_AGENT);
}
__device__ __forceinline__ int aloadi(const int* p) {
    return __hip_atomic_load(p, __ATOMIC_RELAXED, __HIP_MEMORY_SCOPE_AGENT);
}

// ---------------------------------------------------------------------------
// Encoder: 256 blocks = dir(2) x tile(16; 8 batches) x slice(8; 32 units).
// R8 layouts (plain zp, padded hL, float4-broadcast z-core) + slice-matched
// per-wave h loads + stage-A/B gate split + per-wave sub-flags.
// ---------------------------------------------------------------------------
__global__ __attribute__((amdgpu_flat_work_group_size(1024, 1024),
                          amdgpu_waves_per_eu(4, 4)))
void encoder_kernel(const float* __restrict__ x,
                    const float* __restrict__ Wf_k, const float* __restrict__ Wf_r,
                    const float* __restrict__ bf,
                    const float* __restrict__ Wb_k, const float* __restrict__ Wb_r,
                    const float* __restrict__ bb,
                    float* __restrict__ enc, float* __restrict__ h_ex,
                    int* __restrict__ flags)
{
    const int bid  = blockIdx.x;
    const int dir  = bid >> 7;
    const int tile = (bid >> 3) & 15;
    const int jsl  = bid & 7;
    const int grp  = dir * 16 + tile;
    const int bg0  = tile * 8;
    const float* __restrict__ Wk   = dir ? Wb_k : Wf_k;
    const float* __restrict__ Wr   = dir ? Wb_r : Wf_r;
    const float* __restrict__ bias = dir ? bb : bf;
    const int tid = threadIdx.x;
    const int wv  = tid >> 6;
    const int l   = tid & 63;
    const int g0 = ((l >> 5) << 8) + jsl * 32 + (l & 31);

    __shared__ float zp[16][8][128];                // 64 KB (plain, 2-way free)
    __shared__ float __align__(16) hLe[2][8][260];  // 16.6 KB (dbuf, +4 pad)
    __shared__ float zred[8][128];                  // 4 KB
    __shared__ float WkL[5][128];
    __shared__ float biasL[128];
    __shared__ unsigned char mL[8][SEQ];            // 4 KB
    __shared__ float xLe[8][8];

    // ---- one-time staging ----
    for (int i = tid; i < 2 * 8 * 260; i += 1024) ((float*)hLe)[i] = 0.0f;
    if (tid < 128) biasL[tid] = bias[((tid >> 5) << 8) + jsl * 32 + (tid & 31)];
    if (tid >= 128 && tid < 768) {
        int i = tid - 128, c = i >> 7, cl = i & 127;
        WkL[c][cl] = Wk[c * 1024 + ((cl >> 5) << 8) + jsl * 32 + (cl & 31)];
    }
    for (int i = tid; i < 8 * SEQ; i += 1024) {
        int b = i >> 9, tt = i & (SEQ - 1);
        mL[b][tt] = (x[((size_t)((bg0 + b) * CCH) * SEQ + tt) * 3 + 2] != 0.0f) ? 1 : 0;
    }
    // weights -> registers (pinned): rows 16*wv..+15, cols g0 and g0+512
    float wr0[16], wr1[16];
    {
        const float* wbase = Wr + (size_t)(wv * 16) * 1024 + g0;
        #pragma unroll
        for (int r = 0; r < 16; ++r) {
            wr0[r] = wbase[(size_t)r * 1024];
            wr1[r] = wbase[(size_t)r * 1024 + 512];
        }
        #pragma unroll
        for (int r = 0; r < 16; ++r)
            asm volatile("" : "+v"(wr0[r]), "+v"(wr1[r]));
    }
    float creg = 0.0f, hreg = 0.0f;   // gate-thread state (tid<256)
    __syncthreads();

    for (int t = 0; t < SEQ; ++t) {
        const int cur = t & 1;
        const int ts = dir ? (SEQ - 1 - t) : t;
        if (t > 0 && wv < 8) {
            // wave w loads slice w's output: u in [32w,+32), all 8 batches
            if (l < 4) {
                const int* fp = &flags[(grp * 8 + wv) * 32 + l];
                int guard = 0;
                while (aloadi(fp) < t && guard < (1 << 26)) {
                    __builtin_amdgcn_s_sleep(1); ++guard;
                }
            }
            int b = l >> 3, u0 = wv * 32 + (l & 7) * 4;
            const unsigned long long* hsrc = (const unsigned long long*)
                &h_ex[(size_t)(dir * 2 + ((t - 1) & 1)) * 32768
                      + (size_t)(bg0 + b) * UNITS + u0];
            unsigned long long v0 = aloadu64(hsrc);
            unsigned long long v1 = aloadu64(hsrc + 1);
            float4 hv;
            ((unsigned long long*)&hv)[0] = v0;
            ((unsigned long long*)&hv)[1] = v1;
            *(float4*)&hLe[cur][b][u0] = hv;   // b128 write: 8-cycle minimum
        }
        if (tid >= 960 && tid < 1000) {  // wave 15: x_t for the 8 batches
            int i = tid - 960, b = i / 5, c = i - b * 5;
            xLe[b][c] = x[((size_t)((bg0 + b) * CCH + c) * SEQ + ts) * 3];
        }
        __syncthreads();   // B1

        // z-core: 8 batches x (16 rows x 2 cols) per lane (R8 core)
        float accA[8], accB[8];
        #pragma unroll
        for (int b = 0; b < 8; ++b) {
            float a0 = 0.f, a1 = 0.f;
            const float4* hp = (const float4*)&hLe[cur][b][wv * 16];
            #pragma unroll
            for (int q = 0; q < 4; ++q) {
                float4 h4 = hp[q];
                a0 = fmaf(h4.x, wr0[4*q+0], a0); a1 = fmaf(h4.x, wr1[4*q+0], a1);
                a0 = fmaf(h4.y, wr0[4*q+1], a0); a1 = fmaf(h4.y, wr1[4*q+1], a1);
                a0 = fmaf(h4.z, wr0[4*q+2], a0); a1 = fmaf(h4.z, wr1[4*q+2], a1);
                a0 = fmaf(h4.w, wr0[4*q+3], a0); a1 = fmaf(h4.w, wr1[4*q+3], a1);
            }
            accA[b] = a0; accB[b] = a1;
        }
        #pragma unroll
        for (int b = 0; b < 8; ++b) {
            zp[wv][b][l]      = accA[b];
            zp[wv][b][64 + l] = accB[b];
        }
        __syncthreads();   // B2

        // stage-A: 1024 threads, one (b,cl): bias + 16 slots + x@Wk
        {
            int b = tid >> 7, cl = tid & 127;
            float sum = biasL[cl];
            #pragma unroll
            for (int s = 0; s < 16; ++s) sum += zp[s][b][cl];
            #pragma unroll
            for (int c = 0; c < 5; ++c) sum = fmaf(xLe[b][c], WkL[c][cl], sum);
            zred[b][cl] = sum;
        }
        __syncthreads();   // B2b

        if (tid < 256) {   // stage-B: gates + mask + publish; per-wave sub-flag
            int b = tid >> 5, u = tid & 31;
            float zi = zred[b][u];
            float zf = zred[b][32 + u];
            float zg = zred[b][64 + u];
            float zo = zred[b][96 + u];
            float cn = sigmoidf_(zf) * creg + sigmoidf_(zi) * tanhf_(zg);
            float hn = sigmoidf_(zo) * tanhf_(cn);
            int m = mL[b][ts];
            float h2 = m ? hn : hreg;
            float c2 = m ? cn : creg;
            creg = c2; hreg = h2;
            astoref(&h_ex[(size_t)(dir * 2 + cur) * 32768
                          + (size_t)(bg0 + b) * UNITS + jsl * 32 + u], h2);
            enc[((size_t)(bg0 + b) * SEQ + ts) * RU + dir * UNITS + jsl * 32 + u] = h2;
            asm volatile("s_waitcnt vmcnt(0)" ::: "memory");
            if (l == 0) astorei(&flags[(grp * 8 + jsl) * 32 + wv], t + 1);
        }
        // no trailing barrier: hLe dbuf'd; zp/zred rewritten only after next B1/B2
    }
}

// ---------------------------------------------------------------------------
// Attention precompute (alpha constant over decoder time). One block/batch.
// ---------------------------------------------------------------------------
__global__ __launch_bounds__(256)
void attn_kernel(const float* __restrict__ enc,
                 const float* __restrict__ W_attn, const float* __restrict__ b_attn,
                 const float* __restrict__ W_dense, const float* __restrict__ b_dense,
                 const float* __restrict__ x,
                 float* __restrict__ attn_ws, float* __restrict__ hidden_ws,
                 float* __restrict__ xbuf, float* __restrict__ xconst)
{
    const int b = blockIdx.x;
    const int tid = threadIdx.x;
    const int lane = tid & 63;
    const int wv = tid >> 6;

    __shared__ float WeL[RU];
    __shared__ float scoresL[SEQ];
    __shared__ float red[256];
    __shared__ float attnL[RU];

    WeL[tid]       = W_attn[CCH + tid];
    WeL[tid + 256] = W_attn[CCH + tid + 256];
    __syncthreads();

    const float* __restrict__ encb = enc + (size_t)b * SEQ * RU;
    const float batt = b_attn[0];

    for (int s = wv; s < SEQ; s += 4) {
        const float* row = encb + (size_t)s * RU;
        float p = 0.0f;
        #pragma unroll
        for (int i = 0; i < 8; ++i) {
            int d = lane * 8 + i;
            p = fmaf(row[d], WeL[d], p);
        }
        #pragma unroll
        for (int o = 32; o; o >>= 1) p += __shfl_xor(p, o);
        if (lane == 0) scoresL[s] = p + batt;
    }
    __syncthreads();

    float m = fmaxf(scoresL[tid], scoresL[tid + 256]);
    red[tid] = m;
    __syncthreads();
    for (int st = 128; st; st >>= 1) {
        if (tid < st) red[tid] = fmaxf(red[tid], red[tid + st]);
        __syncthreads();
    }
    const float mx = red[0];
    __syncthreads();
    float e0 = __expf(scoresL[tid] - mx);
    float e1 = __expf(scoresL[tid + 256] - mx);
    red[tid] = e0 + e1;
    __syncthreads();
    for (int st = 128; st; st >>= 1) {
        if (tid < st) red[tid] += red[tid + st];
        __syncthreads();
    }
    const float sinv = 1.0f / red[0];
    __syncthreads();
    scoresL[tid]       = e0 * sinv;
    scoresL[tid + 256] = e1 * sinv;
    __syncthreads();

    float a0 = 0.0f, a1 = 0.0f;
    for (int s = 0; s < SEQ; ++s) {
        float al = scoresL[s];
        a0 = fmaf(al, encb[(size_t)s * RU + tid], a0);
        a1 = fmaf(al, encb[(size_t)s * RU + tid + 256], a1);
    }
    attn_ws[(size_t)b * RU + tid]       = a0;
    attn_ws[(size_t)b * RU + tid + 256] = a1;
    attnL[tid] = a0;
    attnL[tid + 256] = a1;
    hidden_ws[(size_t)b * RU + tid]       = encb[(size_t)(SEQ - 1) * RU + tid];
    hidden_ws[(size_t)b * RU + tid + 256] = encb[(size_t)(SEQ - 1) * RU + tid + 256];
    if (tid < CCH) xbuf[b * CCH + tid] = x[((size_t)(b * CCH + tid) * SEQ + 0) * 3];
    __syncthreads();

    if (tid < CCH) {
        float acc = b_dense[tid];
        for (int d = 0; d < RU; ++d)
            acc = fmaf(attnL[d], W_dense[(RU + d) * CCH + tid], acc);
        xconst[b * CCH + tid] = acc;
    }
}

// ---------------------------------------------------------------------------
// Decoder: 256 blocks = tile(16; 8 batches) x slice(16; 32 units).
// R8 core + slice-matched loads + stage split + sub-flags + overlapped dense.
// ---------------------------------------------------------------------------
__global__ __attribute__((amdgpu_flat_work_group_size(1024, 1024),
                          amdgpu_waves_per_eu(4, 4)))
void decoder_kernel(const float* __restrict__ Wd_k, const float* __restrict__ Wd_r,
                    const float* __restrict__ bd,
                    const float* __restrict__ W_dense,
                    const float* __restrict__ attn_ws, const float* __restrict__ hidden_ws,
                    const float* __restrict__ xbuf, const float* __restrict__ xconst,
                    float* __restrict__ h_ex, int* __restrict__ flags,
                    float* __restrict__ out)
{
    const int bid  = blockIdx.x;
    const int tile = bid >> 4;
    const int jsl  = bid & 15;
    const int bg0  = tile * 8;
    const int tid  = threadIdx.x;
    const int wv   = tid >> 6;
    const int l    = tid & 63;
    const int g0 = ((l >> 5) << 9) + jsl * 32 + (l & 31);

    __shared__ float zp[16][8][128];                // 64 KB (plain)
    __shared__ float __align__(16) hL[2][8][516];   // 33 KB (dbuf, +4 pad)
    __shared__ float zred[8][128];                  // 4 KB
    __shared__ float WdL[RU * CCH];                 // 10 KB
    __shared__ float WkL[5][128];                   // 2.5 KB
    __shared__ float biasL[128];
    __shared__ float xL[8][8], xcL[8][8];

    // ---- one-time staging ----
    for (int i = tid; i < RU * CCH; i += 1024) WdL[i] = W_dense[i];
    if (tid < 128) biasL[tid] = bd[((tid >> 5) << 9) + jsl * 32 + (tid & 31)];
    if (tid >= 128 && tid < 768) {
        int i = tid - 128, c = i >> 7, cl = i & 127;
        WkL[c][cl] = Wd_k[c * 2048 + ((cl >> 5) << 9) + jsl * 32 + (cl & 31)];
    }
    if (tid < 64) {
        int b = tid >> 3, c = tid & 7;
        if (c < 5) {
            xL[b][c]  = xbuf[(bg0 + b) * CCH + c];
            xcL[b][c] = xconst[(bg0 + b) * CCH + c];
        }
    }
    {   // t=0 h from hidden_ws
        int f = tid * 4, b = f >> 9, u = f & (RU - 1);
        *(float4*)&hL[0][b][u] = *(const float4*)&hidden_ws[(size_t)(bg0 + b) * RU + u];
    }
    // att value for gate thread (b,u) in a register
    float attR = 0.0f;
    if (tid < 256)
        attR = attn_ws[(size_t)(bg0 + (tid >> 5)) * RU + jsl * 32 + (tid & 31)];
    // weights -> registers (pinned): rows 32*wv..+31, cols g0 and g0+1024
    float wr0[32], wr1[32];
    {
        const float* wbase = Wd_r + (size_t)(wv * 32) * 2048 + g0;
        #pragma unroll
        for (int r = 0; r < 32; ++r) {
            wr0[r] = wbase[(size_t)r * 2048];
            wr1[r] = wbase[(size_t)r * 2048 + 1024];
        }
        #pragma unroll
        for (int r = 0; r < 32; ++r)
            asm volatile("" : "+v"(wr0[r]), "+v"(wr1[r]));
    }
    __syncthreads();

    for (int t = 0; t < SEQ - 1; ++t) {
        const int cur = t & 1;
        if (t > 0) {
            // wave w loads slice w's output: u in [32w,+32), all 8 batches
            if (l < 4) {
                const int* fp = &flags[(tile * 16 + wv) * 32 + l];
                int guard = 0;
                while (aloadi(fp) < t && guard < (1 << 26)) {
                    __builtin_amdgcn_s_sleep(1); ++guard;
                }
            }
            int b = l >> 3, u0 = wv * 32 + (l & 7) * 4;
            const unsigned long long* hsrc = (const unsigned long long*)
                &h_ex[(size_t)((t - 1) & 1) * 65536 + (size_t)(bg0 + b) * RU + u0];
            unsigned long long v0 = aloadu64(hsrc);
            unsigned long long v1 = aloadu64(hsrc + 1);
            float4 hv;
            ((unsigned long long*)&hv)[0] = v0;
            ((unsigned long long*)&hv)[1] = v1;
            *(float4*)&hL[cur][b][u0] = hv;
        }
        __syncthreads();   // B1

        // x_t dense-reduce (needs only h): overlapped with z-partial phase
        if (t > 0) {
            for (int it = wv; it < 40; it += 16) {
                int bb = it / 5, c = it - bb * 5;
                float p = 0.f;
                #pragma unroll
                for (int q = 0; q < 8; ++q) {
                    int uu = l + (q << 6);
                    p = fmaf(hL[cur][bb][uu], WdL[uu * CCH + c], p);
                }
                #pragma unroll
                for (int o = 32; o; o >>= 1) p += __shfl_xor(p, o);
                if (l == 0) xL[bb][c] = p + xcL[bb][c];
            }
        }

        // z-core: 8 batches x (32 rows x 2 cols) per lane (R8 core)
        float accA[8], accB[8];
        #pragma unroll
        for (int b = 0; b < 8; ++b) {
            float a0 = 0.f, a1 = 0.f;
            const float4* hp = (const float4*)&hL[cur][b][wv * 32];
            #pragma unroll
            for (int q = 0; q < 8; ++q) {
                float4 h4 = hp[q];
                a0 = fmaf(h4.x, wr0[4*q+0], a0); a1 = fmaf(h4.x, wr1[4*q+0], a1);
                a0 = fmaf(h4.y, wr0[4*q+1], a0); a1 = fmaf(h4.y, wr1[4*q+1], a1);
                a0 = fmaf(h4.z, wr0[4*q+2], a0); a1 = fmaf(h4.z, wr1[4*q+2], a1);
                a0 = fmaf(h4.w, wr0[4*q+3], a0); a1 = fmaf(h4.w, wr1[4*q+3], a1);
            }
            accA[b] = a0; accB[b] = a1;
        }
        #pragma unroll
        for (int b = 0; b < 8; ++b) {
            zp[wv][b][l]      = accA[b];
            zp[wv][b][64 + l] = accB[b];
        }
        __syncthreads();   // B2

        // stage-A: 1024 threads, one (b,cl): bias + 16 slots + x@Wk
        {
            int b = tid >> 7, cl = tid & 127;
            float sum = biasL[cl];
            #pragma unroll
            for (int s = 0; s < 16; ++s) sum += zp[s][b][cl];
            #pragma unroll
            for (int c = 0; c < 5; ++c) sum = fmaf(xL[b][c], WkL[c][cl], sum);
            zred[b][cl] = sum;
        }
        __syncthreads();   // B2b

        if (tid < 256) {   // stage-B: gates + publish h; per-wave sub-flag
            int b = tid >> 5, u = tid & 31;
            float zi = zred[b][u];
            float zf = zred[b][32 + u];
            float zg = zred[b][64 + u];
            float zo = zred[b][96 + u];
            float cn = sigmoidf_(zf) * attR + sigmoidf_(zi) * tanhf_(zg);
            float hn = sigmoidf_(zo) * tanhf_(cn);
            astoref(&h_ex[(size_t)cur * 65536
                          + (size_t)(bg0 + b) * RU + jsl * 32 + u], hn);
            asm volatile("s_waitcnt vmcnt(0)" ::: "memory");
            if (l == 0) astorei(&flags[(tile * 16 + jsl) * 32 + wv], t + 1);
        }
        // out-write off the drain path (xL stable until after next B1)
        if (t > 0 && jsl == 0 && tid >= 256 && tid < 296) {
            int i = tid - 256, bb = i / 5, c = i - bb * 5;
            out[(size_t)((bg0 + bb) * CCH + c) * (SEQ - 1) + (t - 1)] = xL[bb][c];
        }
    }

    // ---- epilogue: out[510] from h_511 (jsl==0 blocks only) ----
    if (jsl == 0) {
        const int t = SEQ - 1;          // 511
        const int cur = t & 1;          // 1
        if (l < 4) {
            const int* fp = &flags[(tile * 16 + wv) * 32 + l];
            int guard = 0;
            while (aloadi(fp) < t && guard < (1 << 26)) {
                __builtin_amdgcn_s_sleep(1); ++guard;
            }
        }
        int b = l >> 3, u0 = wv * 32 + (l & 7) * 4;
        const unsigned long long* hsrc = (const unsigned long long*)
            &h_ex[(size_t)((t - 1) & 1) * 65536 + (size_t)(bg0 + b) * RU + u0];
        unsigned long long v0 = aloadu64(hsrc);
        unsigned long long v1 = aloadu64(hsrc + 1);
        float4 hv;
        ((unsigned long long*)&hv)[0] = v0;
        ((unsigned long long*)&hv)[1] = v1;
        *(float4*)&hL[cur][b][u0] = hv;
        __syncthreads();
        for (int it = wv; it < 40; it += 16) {
            int bb = it / 5, c = it - bb * 5;
            float p = 0.f;
            #pragma unroll
            for (int q = 0; q < 8; ++q) {
                int uu = l + (q << 6);
                p = fmaf(hL[cur][bb][uu], WdL[uu * CCH + c], p);
            }
            #pragma unroll
            for (int o = 32; o; o >>= 1) p += __shfl_xor(p, o);
            if (l == 0)
                out[(size_t)((bg0 + bb) * CCH + c) * (SEQ - 1) + (t - 1)]
                    = p + xcL[bb][c];
        }
    }
}

// ---------------------------------------------------------------------------
extern "C" void kernel_launch(void* const* d_in, const int* in_sizes, int n_in,
                              void* d_out, int out_size, void* d_ws, size_t ws_size,
                              hipStream_t stream)
{
    const float* x       = (const float*)d_in[0];
    const float* Wf_k    = (const float*)d_in[1];
    const float* Wf_r    = (const float*)d_in[2];
    const float* bf      = (const float*)d_in[3];
    const float* Wb_k    = (const float*)d_in[4];
    const float* Wb_r    = (const float*)d_in[5];
    const float* bb      = (const float*)d_in[6];
    const float* Wd_k    = (const float*)d_in[7];
    const float* Wd_r    = (const float*)d_in[8];
    const float* bd      = (const float*)d_in[9];
    const float* W_attn  = (const float*)d_in[10];
    const float* b_attn  = (const float*)d_in[11];
    const float* W_dense = (const float*)d_in[12];
    const float* b_dense = (const float*)d_in[13];
    float* out = (float*)d_out;

    float* ws = (float*)d_ws;
    // persistent (attn -> decoder) region after enc
    float* enc      = ws;                          // [0, ENC_N)
    float* attn_p   = ws + ENC_N;                  // 65536 floats
    float* hidden_p = ws + ENC_N + 65536;          // 65536 floats
    float* xbuf_p   = ws + ENC_N + 131072;         // 640
    float* xconst_p = ws + ENC_N + 131712;         // 640
    // encoder-phase overlays (dead before attn_kernel writes the same region)
    float* h_ex_e   = ws + ENC_N;                  // 4 x 128 x 256 = 131072 floats
    int*   flag_e   = (int*)(ws + ENC_N + 131072); // 32grp x 8sl x 32 = 8192 ints
    // decoder-phase overlays on dead enc region
    int*   flag_d   = (int*)ws;                    // 16tile x 16sl x 32 = 8192 ints
    float* h_ex_d   = ws + 8192;                   // 2 x 128 x 512 = 131072 floats

    hipMemsetAsync(flag_e, 0, 8192 * sizeof(int), stream);
    encoder_kernel<<<256, 1024, 0, stream>>>(x, Wf_k, Wf_r, bf, Wb_k, Wb_r, bb,
                                             enc, h_ex_e, flag_e);
    attn_kernel<<<BATCH, 256, 0, stream>>>(enc, W_attn, b_attn, W_dense, b_dense, x,
                                           attn_p, hidden_p, xbuf_p, xconst_p);
    hipMemsetAsync(flag_d, 0, 8192 * sizeof(int), stream);
    decoder_kernel<<<256, 1024, 0, stream>>>(Wd_k, Wd_r, bd, W_dense,
                                             attn_p, hidden_p, xbuf_p, xconst_p,
                                             h_ex_d, flag_d, out);
}